// Round 2
// baseline (552.232 us; speedup 1.0000x reference)
//
#include <hip/hip_runtime.h>

#define BATCH 16
#define CIN   200
#define T1    8192
#define COUTC 400
#define TT2   4096
#define NJ    25
#define NGROUP 10
#define CPG   40
#define NPOOL 14

__constant__ int NBR_OFF[NJ + 1] = {0,8,14,18,21,29,35,39,42,50,56,63,72,80,85,94,101,106,110,113,122,129,134,138,141,145};
__constant__ int NBR[145] = {
 0,1,2,4,5,8,9,24,
 0,1,2,3,4,8,
 0,1,2,3,
 1,2,3,
 0,1,4,5,6,8,9,24,
 0,4,5,6,7,8,
 4,5,6,7,
 5,6,7,
 0,1,4,5,8,9,10,24,
 0,4,8,9,10,11,
 8,9,10,11,12,14,19,
 9,10,11,12,13,14,15,19,20,
 10,11,12,13,14,15,19,20,
 11,12,13,14,19,
 10,11,12,13,14,15,16,19,20,
 11,12,14,15,16,17,19,
 14,15,16,17,18,
 15,16,17,18,
 16,17,18,
 10,11,12,13,14,15,19,20,21,
 11,12,14,19,20,21,22,
 19,20,21,22,23,
 20,21,22,23,
 21,22,23,
 0,4,8,24};
__constant__ int PAIR_A[NPOOL] = {0,2,4,6,8,10,12,14,15,17,19,20,22,24};
__constant__ int PAIR_B[NPOOL] = {1,3,5,7,9,11,13,-1,16,18,-1,21,23,-1};

// ---------------- Kernel A: conv0 (K=3, s=1, reflect pad 1) + PReLU, 4 t/thread ----
// grid (8, 25, 16), block 256.  out h0: (B, 200, 8192)
__global__ __launch_bounds__(256) void conv0_prelu(
    const float* __restrict__ x, const float* __restrict__ w0,
    const float* __restrict__ b0, const float* __restrict__ a0,
    float* __restrict__ h0)
{
    const int jo  = blockIdx.y;
    const int b   = blockIdx.z;
    const int tid = threadIdx.x;
    const int t0  = (blockIdx.x * 256 + tid) * 4;

    const int off  = NBR_OFF[jo];
    const int nci  = (NBR_OFF[jo + 1] - off) * 8;

    __shared__ float wl[72 * 24];   // [cl][k][oc]  (k*8+oc)
    __shared__ int   cil[72];
    __shared__ float bl[8];

    for (int i = tid; i < nci; i += 256)
        cil[i] = NBR[off + (i >> 3)] * 8 + (i & 7);
    const int wtot = nci * 24;
    for (int idx = tid; idx < wtot; idx += 256) {
        int cl = idx / 24;
        int r  = idx - cl * 24;
        int k  = r >> 3;
        int oc = r & 7;
        int ci = NBR[off + (cl >> 3)] * 8 + (cl & 7);
        wl[idx] = w0[(size_t)(jo * 8 + oc) * (CIN * 3) + ci * 3 + k];
    }
    if (tid < 8) bl[tid] = b0[jo * 8 + tid];
    __syncthreads();

    const float alpha = a0[0];
    float acc[8][4];
#pragma unroll
    for (int oc = 0; oc < 8; ++oc)
#pragma unroll
        for (int i = 0; i < 4; ++i) acc[oc][i] = bl[oc];

    const bool first = (t0 == 0);
    const bool last  = (t0 + 4 == T1);
    const float* xb = x + (size_t)b * CIN * T1;

    for (int cl = 0; cl < nci; ++cl) {
        const float* xc = xb + (size_t)cil[cl] * T1;
        float4 v = *(const float4*)(xc + t0);
        float xs[6];
        xs[1] = v.x; xs[2] = v.y; xs[3] = v.z; xs[4] = v.w;
        xs[0] = first ? v.y : xc[t0 - 1];
        xs[5] = last  ? v.z : xc[t0 + 4];
        const float* w = &wl[cl * 24];
#pragma unroll
        for (int oc = 0; oc < 8; ++oc) {
            float wa = w[oc], wb = w[8 + oc], wc = w[16 + oc];
#pragma unroll
            for (int i = 0; i < 4; ++i)
                acc[oc][i] += wa * xs[i] + wb * xs[i + 1] + wc * xs[i + 2];
        }
    }

    float* hb = h0 + ((size_t)b * CIN + jo * 8) * T1 + t0;
#pragma unroll
    for (int oc = 0; oc < 8; ++oc) {
        float4 o;
        o.x = acc[oc][0] >= 0.f ? acc[oc][0] : alpha * acc[oc][0];
        o.y = acc[oc][1] >= 0.f ? acc[oc][1] : alpha * acc[oc][1];
        o.z = acc[oc][2] >= 0.f ? acc[oc][2] : alpha * acc[oc][2];
        o.w = acc[oc][3] >= 0.f ? acc[oc][3] : alpha * acc[oc][3];
        *(float4*)(hb + (size_t)oc * T1) = o;
    }
}

// ---------------- Kernel B: conv1 (K=3, s=2, reflect pad 1), 4 t2/thread ----------
// grid (4, 25, 16), block 256.  out h1: (B, 400, 4096)
__global__ __launch_bounds__(256) void conv1_k(
    const float* __restrict__ h0, const float* __restrict__ w1,
    const float* __restrict__ b1, float* __restrict__ h1)
{
    const int jo  = blockIdx.y;
    const int b   = blockIdx.z;
    const int tid = threadIdx.x;
    const int t0  = (blockIdx.x * 256 + tid) * 4;  // t2 base

    const int off = NBR_OFF[jo];
    const int nci = (NBR_OFF[jo + 1] - off) * 8;

    __shared__ float wl[72 * 48];   // [cl][k][oc]  (k*16+oc)
    __shared__ int   cil[72];
    __shared__ float bl[16];

    for (int i = tid; i < nci; i += 256)
        cil[i] = NBR[off + (i >> 3)] * 8 + (i & 7);
    const int wtot = nci * 48;
    for (int idx = tid; idx < wtot; idx += 256) {
        int cl = idx / 48;
        int r  = idx - cl * 48;
        int k  = r >> 4;
        int oc = r & 15;
        int ci = NBR[off + (cl >> 3)] * 8 + (cl & 7);
        wl[idx] = w1[(size_t)(jo * 16 + oc) * (CIN * 3) + ci * 3 + k];
    }
    if (tid < 16) bl[tid] = b1[jo * 16 + tid];
    __syncthreads();

    float acc[16][4];
#pragma unroll
    for (int oc = 0; oc < 16; ++oc)
#pragma unroll
        for (int i = 0; i < 4; ++i) acc[oc][i] = bl[oc];

    const int p = 2 * t0;
    const bool first = (p == 0);
    const float* hb = h0 + (size_t)b * CIN * T1;

    for (int cl = 0; cl < nci; ++cl) {
        const float* xc = hb + (size_t)cil[cl] * T1;
        float4 A  = *(const float4*)(xc + p);
        float4 Bv = *(const float4*)(xc + p + 4);
        float xs[9];
        xs[1] = A.x; xs[2] = A.y; xs[3] = A.z; xs[4] = A.w;
        xs[5] = Bv.x; xs[6] = Bv.y; xs[7] = Bv.z; xs[8] = Bv.w;
        xs[0] = first ? A.y : xc[p - 1];
        const float* w = &wl[cl * 48];
#pragma unroll
        for (int oc = 0; oc < 16; ++oc) {
            float wa = w[oc], wb = w[16 + oc], wc = w[32 + oc];
#pragma unroll
            for (int i = 0; i < 4; ++i)
                acc[oc][i] += wa * xs[2 * i] + wb * xs[2 * i + 1] + wc * xs[2 * i + 2];
        }
    }

    float* ob = h1 + ((size_t)b * COUTC + jo * 16) * TT2 + t0;
#pragma unroll
    for (int oc = 0; oc < 16; ++oc) {
        float4 o;
        o.x = acc[oc][0]; o.y = acc[oc][1]; o.z = acc[oc][2]; o.w = acc[oc][3];
        *(float4*)(ob + (size_t)oc * TT2) = o;
    }
}

// ---------------- Kernel C: GroupNorm partial sums (deterministic) ----------------
// grid (32, 10, 16), block 256.  part[b][g][slice][2]
__global__ __launch_bounds__(256) void gn_part(
    const float* __restrict__ h1, float* __restrict__ part)
{
    const int sl = blockIdx.x, g = blockIdx.y, b = blockIdx.z;
    const int tid = threadIdx.x;
    const int t0 = sl * (TT2 / 32);   // 128 per slice

    const float* base = h1 + (size_t)b * COUTC * TT2 + (size_t)g * CPG * TT2;
    float s = 0.f, ss = 0.f;
    for (int i = tid; i < CPG * 32; i += 256) {   // 32 float4 per channel row
        int c  = i >> 5;
        int t4 = i & 31;
        float4 v = *(const float4*)(base + (size_t)c * TT2 + t0 + 4 * t4);
        s  += v.x + v.y + v.z + v.w;
        ss += v.x * v.x + v.y * v.y + v.z * v.z + v.w * v.w;
    }
    for (int o = 32; o; o >>= 1) {
        s  += __shfl_down(s, o, 64);
        ss += __shfl_down(ss, o, 64);
    }
    __shared__ float rs[4], rss[4];
    const int lane = tid & 63, wv = tid >> 6;
    if (lane == 0) { rs[wv] = s; rss[wv] = ss; }
    __syncthreads();
    if (tid == 0) {
        float S  = rs[0] + rs[1] + rs[2] + rs[3];
        float SS = rss[0] + rss[1] + rss[2] + rss[3];
        size_t o = (((size_t)b * NGROUP + g) * 32 + sl) * 2;
        part[o] = S;
        part[o + 1] = SS;
    }
}

// ---------------- Kernel D: finalize stats ----------------
__global__ void gn_final(const float* __restrict__ part, float* __restrict__ stats)
{
    int i = threadIdx.x;
    if (i < BATCH * NGROUP) {
        float s = 0.f, ss = 0.f;
        for (int k = 0; k < 32; ++k) {
            s  += part[((size_t)i * 32 + k) * 2];
            ss += part[((size_t)i * 32 + k) * 2 + 1];
        }
        const float invN = 1.0f / (float)(CPG * TT2);
        float mean = s * invN;
        float var  = ss * invN - mean * mean;
        stats[i * 2]     = mean;
        stats[i * 2 + 1] = rsqrtf(var + 1e-5f);
    }
}

// ---------------- Kernel E: gn + shortcut conv(K=1,s=2) + pool + PReLU, 4 t2/thread
// grid (4, 14, 16), block 256.  out: (B, 224, 4096)
__global__ __launch_bounds__(256) void final_k(
    const float* __restrict__ x, const float* __restrict__ h1,
    const float* __restrict__ stats, const float* __restrict__ gamma,
    const float* __restrict__ beta, const float* __restrict__ ws,
    const float* __restrict__ bs, const float* __restrict__ a1,
    float* __restrict__ out)
{
    const int n  = blockIdx.y;
    const int b  = blockIdx.z;
    const int tid = threadIdx.x;
    const int t0 = (blockIdx.x * 256 + tid) * 4;

    int js[2];
    js[0] = PAIR_A[n];
    const int jb = PAIR_B[n];
    const int L = (jb >= 0) ? 2 : 1;
    js[1] = (jb >= 0) ? jb : js[0];

    __shared__ float wsl[2][72 * 16];
    __shared__ int   cill[2][72];
    __shared__ float gl[2][16], btl[2][16], bsl[2][16], ml[2][16], rl[2][16];

    for (int ji = 0; ji < L; ++ji) {
        const int j   = js[ji];
        const int off = NBR_OFF[j];
        const int nci = (NBR_OFF[j + 1] - off) * 8;
        for (int i = tid; i < nci; i += 256)
            cill[ji][i] = NBR[off + (i >> 3)] * 8 + (i & 7);
        for (int idx = tid; idx < nci * 16; idx += 256) {
            int cl = idx >> 4;
            int c  = idx & 15;
            int ci = NBR[off + (cl >> 3)] * 8 + (cl & 7);
            wsl[ji][idx] = ws[(size_t)(j * 16 + c) * CIN + ci];
        }
        if (tid < 16) {
            int ch = j * 16 + tid;
            gl[ji][tid]  = gamma[ch];
            btl[ji][tid] = beta[ch];
            bsl[ji][tid] = bs[ch];
            int g = ch / CPG;
            ml[ji][tid] = stats[((size_t)b * NGROUP + g) * 2];
            rl[ji][tid] = stats[((size_t)b * NGROUP + g) * 2 + 1];
        }
    }
    __syncthreads();

    const float alpha = a1[0];
    const float* xb  = x  + (size_t)b * CIN * T1;
    const float* h1b = h1 + (size_t)b * COUTC * TT2;
    const int p = 2 * t0;

    float acc[16][4];
#pragma unroll
    for (int c = 0; c < 16; ++c)
#pragma unroll
        for (int i = 0; i < 4; ++i) acc[c][i] = 0.f;

    for (int ji = 0; ji < L; ++ji) {
        const int j   = js[ji];
        const int nci = (NBR_OFF[j + 1] - NBR_OFF[j]) * 8;
        // shortcut bias
#pragma unroll
        for (int c = 0; c < 16; ++c)
#pragma unroll
            for (int i = 0; i < 4; ++i) acc[c][i] += bsl[ji][c];
        // shortcut conv K=1 stride 2 (even positions p, p+2, p+4, p+6)
        for (int cl = 0; cl < nci; ++cl) {
            const float* xc = xb + (size_t)cill[ji][cl] * T1;
            float4 A  = *(const float4*)(xc + p);
            float4 Bv = *(const float4*)(xc + p + 4);
            float xv[4] = {A.x, A.z, Bv.x, Bv.z};
            const float* wr = &wsl[ji][cl * 16];
#pragma unroll
            for (int c = 0; c < 16; ++c) {
                float w = wr[c];
#pragma unroll
                for (int i = 0; i < 4; ++i) acc[c][i] += w * xv[i];
            }
        }
        // groupnorm term
#pragma unroll
        for (int c = 0; c < 16; ++c) {
            float4 hv = *(const float4*)(h1b + (size_t)(j * 16 + c) * TT2 + t0);
            float m = ml[ji][c], r = rl[ji][c] * gl[ji][c], bt = btl[ji][c];
            acc[c][0] += (hv.x - m) * r + bt;
            acc[c][1] += (hv.y - m) * r + bt;
            acc[c][2] += (hv.z - m) * r + bt;
            acc[c][3] += (hv.w - m) * r + bt;
        }
    }

    const float invL = 1.0f / (float)L;
    float* ob = out + ((size_t)b * 224 + (size_t)n * 16) * TT2 + t0;
#pragma unroll
    for (int c = 0; c < 16; ++c) {
        float4 o;
#pragma unroll
        for (int i = 0; i < 4; ++i) {
            float v = acc[c][i] * invL;
            ((float*)&o)[i] = (v >= 0.f) ? v : alpha * v;
        }
        *(float4*)(ob + (size_t)c * TT2) = o;
    }
}

extern "C" void kernel_launch(void* const* d_in, const int* in_sizes, int n_in,
                              void* d_out, int out_size, void* d_ws, size_t ws_size,
                              hipStream_t stream) {
    const float* x     = (const float*)d_in[0];
    const float* w0    = (const float*)d_in[1];
    const float* b0    = (const float*)d_in[2];
    const float* a0    = (const float*)d_in[3];
    const float* w1    = (const float*)d_in[4];
    const float* b1    = (const float*)d_in[5];
    const float* gamma = (const float*)d_in[6];
    const float* beta  = (const float*)d_in[7];
    const float* ws    = (const float*)d_in[8];
    const float* bs    = (const float*)d_in[9];
    const float* a1    = (const float*)d_in[10];
    float* out = (float*)d_out;

    float* h0    = (float*)d_ws;
    float* h1    = h0 + (size_t)BATCH * CIN * T1;
    float* part  = h1 + (size_t)BATCH * COUTC * TT2;
    float* stats = part + (size_t)BATCH * NGROUP * 32 * 2;

    conv0_prelu<<<dim3(T1 / 1024, NJ, BATCH), 256, 0, stream>>>(x, w0, b0, a0, h0);
    conv1_k<<<dim3(TT2 / 1024, NJ, BATCH), 256, 0, stream>>>(h0, w1, b1, h1);
    gn_part<<<dim3(32, NGROUP, BATCH), 256, 0, stream>>>(h1, part);
    gn_final<<<1, 256, 0, stream>>>(part, stats);
    final_k<<<dim3(TT2 / 1024, NPOOL, BATCH), 256, 0, stream>>>(x, h1, stats, gamma, beta, ws, bs, a1, out);
}

// Round 3
// 542.254 us; speedup vs baseline: 1.0184x; 1.0184x over previous
//
#include <hip/hip_runtime.h>

#define BATCH 16
#define CIN   200
#define T1    8192
#define COUTC 400
#define TT2   4096
#define NJ    25
#define NGROUP 10
#define CPG   40
#define NPOOL 14

__constant__ int NBR_OFF[NJ + 1] = {0,8,14,18,21,29,35,39,42,50,56,63,72,80,85,94,101,106,110,113,122,129,134,138,141,145};
__constant__ int NBR[145] = {
 0,1,2,4,5,8,9,24,
 0,1,2,3,4,8,
 0,1,2,3,
 1,2,3,
 0,1,4,5,6,8,9,24,
 0,4,5,6,7,8,
 4,5,6,7,
 5,6,7,
 0,1,4,5,8,9,10,24,
 0,4,8,9,10,11,
 8,9,10,11,12,14,19,
 9,10,11,12,13,14,15,19,20,
 10,11,12,13,14,15,19,20,
 11,12,13,14,19,
 10,11,12,13,14,15,16,19,20,
 11,12,14,15,16,17,19,
 14,15,16,17,18,
 15,16,17,18,
 16,17,18,
 10,11,12,13,14,15,19,20,21,
 11,12,14,19,20,21,22,
 19,20,21,22,23,
 20,21,22,23,
 21,22,23,
 0,4,8,24};
__constant__ int PAIR_A[NPOOL] = {0,2,4,6,8,10,12,14,15,17,19,20,22,24};
__constant__ int PAIR_B[NPOOL] = {1,3,5,7,9,11,13,-1,16,18,-1,21,23,-1};

// ---------------- Kernel A: conv0 (K=3, s=1, reflect pad 1) + PReLU, 4 t/thread ----
// grid (8, 25, 16), block 256.  out h0: (B, 200, 8192)
__global__ __launch_bounds__(256) void conv0_prelu(
    const float* __restrict__ x, const float* __restrict__ w0,
    const float* __restrict__ b0, const float* __restrict__ a0,
    float* __restrict__ h0)
{
    const int jo  = blockIdx.y;
    const int b   = blockIdx.z;
    const int tid = threadIdx.x;
    const int t0  = (blockIdx.x * 256 + tid) * 4;

    const int off  = NBR_OFF[jo];
    const int nci  = (NBR_OFF[jo + 1] - off) * 8;

    __shared__ float wl[72 * 24];   // [cl][k][oc]
    __shared__ int   cil[72];
    __shared__ float bl[8];

    for (int i = tid; i < nci; i += 256)
        cil[i] = NBR[off + (i >> 3)] * 8 + (i & 7);
    const int wtot = nci * 24;
    for (int idx = tid; idx < wtot; idx += 256) {
        int cl = idx / 24;
        int r  = idx - cl * 24;
        int k  = r >> 3;
        int oc = r & 7;
        int ci = NBR[off + (cl >> 3)] * 8 + (cl & 7);
        wl[idx] = w0[(size_t)(jo * 8 + oc) * (CIN * 3) + ci * 3 + k];
    }
    if (tid < 8) bl[tid] = b0[jo * 8 + tid];
    __syncthreads();

    const float alpha = a0[0];
    float acc[8][4];
#pragma unroll
    for (int oc = 0; oc < 8; ++oc)
#pragma unroll
        for (int i = 0; i < 4; ++i) acc[oc][i] = bl[oc];

    const bool first = (t0 == 0);
    const bool last  = (t0 + 4 == T1);
    const float* xb = x + (size_t)b * CIN * T1;

    for (int cl = 0; cl < nci; ++cl) {
        const float* xc = xb + (size_t)cil[cl] * T1;
        float4 v = *(const float4*)(xc + t0);
        float xs[6];
        xs[1] = v.x; xs[2] = v.y; xs[3] = v.z; xs[4] = v.w;
        xs[0] = first ? v.y : xc[t0 - 1];
        xs[5] = last  ? v.z : xc[t0 + 4];
        const float* w = &wl[cl * 24];
#pragma unroll
        for (int oc = 0; oc < 8; ++oc) {
            float wa = w[oc], wb = w[8 + oc], wc = w[16 + oc];
#pragma unroll
            for (int i = 0; i < 4; ++i)
                acc[oc][i] += wa * xs[i] + wb * xs[i + 1] + wc * xs[i + 2];
        }
    }

    float* hb = h0 + ((size_t)b * CIN + jo * 8) * T1 + t0;
#pragma unroll
    for (int oc = 0; oc < 8; ++oc) {
        float4 o;
        o.x = acc[oc][0] >= 0.f ? acc[oc][0] : alpha * acc[oc][0];
        o.y = acc[oc][1] >= 0.f ? acc[oc][1] : alpha * acc[oc][1];
        o.z = acc[oc][2] >= 0.f ? acc[oc][2] : alpha * acc[oc][2];
        o.w = acc[oc][3] >= 0.f ? acc[oc][3] : alpha * acc[oc][3];
        *(float4*)(hb + (size_t)oc * T1) = o;
    }
}

// ---------------- Kernel B: conv1 (K=3, s=2, reflect pad 1) + GN partials ---------
// grid (4, 25, 16), block 256.  out h1: (B, 400, 4096), part[b][50][4][2]
__global__ __launch_bounds__(256) void conv1_gn(
    const float* __restrict__ h0, const float* __restrict__ w1,
    const float* __restrict__ b1, float* __restrict__ h1,
    float* __restrict__ part)
{
    const int jo  = blockIdx.y;
    const int b   = blockIdx.z;
    const int tid = threadIdx.x;
    const int t0  = (blockIdx.x * 256 + tid) * 4;

    const int off = NBR_OFF[jo];
    const int nci = (NBR_OFF[jo + 1] - off) * 8;

    __shared__ float wl[72 * 48];
    __shared__ int   cil[72];
    __shared__ float bl[16];
    __shared__ float red[4][4];

    for (int i = tid; i < nci; i += 256)
        cil[i] = NBR[off + (i >> 3)] * 8 + (i & 7);
    const int wtot = nci * 48;
    for (int idx = tid; idx < wtot; idx += 256) {
        int cl = idx / 48;
        int r  = idx - cl * 48;
        int k  = r >> 4;
        int oc = r & 15;
        int ci = NBR[off + (cl >> 3)] * 8 + (cl & 7);
        wl[idx] = w1[(size_t)(jo * 16 + oc) * (CIN * 3) + ci * 3 + k];
    }
    if (tid < 16) bl[tid] = b1[jo * 16 + tid];
    __syncthreads();

    float acc[16][4];
#pragma unroll
    for (int oc = 0; oc < 16; ++oc)
#pragma unroll
        for (int i = 0; i < 4; ++i) acc[oc][i] = bl[oc];

    const int p = 2 * t0;
    const bool first = (p == 0);
    const float* hb = h0 + (size_t)b * CIN * T1;

    for (int cl = 0; cl < nci; ++cl) {
        const float* xc = hb + (size_t)cil[cl] * T1;
        float4 A  = *(const float4*)(xc + p);
        float4 Bv = *(const float4*)(xc + p + 4);
        float xs[9];
        xs[1] = A.x; xs[2] = A.y; xs[3] = A.z; xs[4] = A.w;
        xs[5] = Bv.x; xs[6] = Bv.y; xs[7] = Bv.z; xs[8] = Bv.w;
        xs[0] = first ? A.y : xc[p - 1];
        const float* w = &wl[cl * 48];
#pragma unroll
        for (int oc = 0; oc < 16; ++oc) {
            float wa = w[oc], wb = w[16 + oc], wc = w[32 + oc];
#pragma unroll
            for (int i = 0; i < 4; ++i)
                acc[oc][i] += wa * xs[2 * i] + wb * xs[2 * i + 1] + wc * xs[2 * i + 2];
        }
    }

    float* ob = h1 + ((size_t)b * COUTC + jo * 16) * TT2 + t0;
#pragma unroll
    for (int oc = 0; oc < 16; ++oc) {
        float4 o;
        o.x = acc[oc][0]; o.y = acc[oc][1]; o.z = acc[oc][2]; o.w = acc[oc][3];
        *(float4*)(ob + (size_t)oc * TT2) = o;
    }

    // ---- GN partial sums, per 8-channel half (sub-block sb = jo*2+h) ----
    float s0 = 0.f, ss0 = 0.f, s1 = 0.f, ss1 = 0.f;
#pragma unroll
    for (int oc = 0; oc < 8; ++oc)
#pragma unroll
        for (int i = 0; i < 4; ++i) { float v = acc[oc][i]; s0 += v; ss0 += v * v; }
#pragma unroll
    for (int oc = 8; oc < 16; ++oc)
#pragma unroll
        for (int i = 0; i < 4; ++i) { float v = acc[oc][i]; s1 += v; ss1 += v * v; }

    for (int o = 32; o; o >>= 1) {
        s0  += __shfl_down(s0, o, 64);
        ss0 += __shfl_down(ss0, o, 64);
        s1  += __shfl_down(s1, o, 64);
        ss1 += __shfl_down(ss1, o, 64);
    }
    const int lane = tid & 63, wv = tid >> 6;
    if (lane == 0) { red[wv][0] = s0; red[wv][1] = ss0; red[wv][2] = s1; red[wv][3] = ss1; }
    __syncthreads();
    if (tid == 0) {
        float S0 = red[0][0] + red[1][0] + red[2][0] + red[3][0];
        float SS0 = red[0][1] + red[1][1] + red[2][1] + red[3][1];
        float S1 = red[0][2] + red[1][2] + red[2][2] + red[3][2];
        float SS1 = red[0][3] + red[1][3] + red[2][3] + red[3][3];
        const int xblk = blockIdx.x;
        size_t o0 = (((size_t)b * 50 + jo * 2 + 0) * 4 + xblk) * 2;
        size_t o1 = (((size_t)b * 50 + jo * 2 + 1) * 4 + xblk) * 2;
        part[o0] = S0; part[o0 + 1] = SS0;
        part[o1] = S1; part[o1 + 1] = SS1;
    }
}

// ---------------- Kernel C: shortcut conv (K=1, s=2) + bias → s buffer ------------
// grid (4, 25, 16), block 256.  s: (B, 400, 4096)  (aliases h0 storage)
__global__ __launch_bounds__(256) void shortcut_k(
    const float* __restrict__ x, const float* __restrict__ ws,
    const float* __restrict__ bs, float* __restrict__ s)
{
    const int jo  = blockIdx.y;
    const int b   = blockIdx.z;
    const int tid = threadIdx.x;
    const int t0  = (blockIdx.x * 256 + tid) * 4;

    const int off = NBR_OFF[jo];
    const int nci = (NBR_OFF[jo + 1] - off) * 8;

    __shared__ float wsl[72 * 16];
    __shared__ int   cil[72];
    __shared__ float bsl[16];

    for (int i = tid; i < nci; i += 256)
        cil[i] = NBR[off + (i >> 3)] * 8 + (i & 7);
    for (int idx = tid; idx < nci * 16; idx += 256) {
        int cl = idx >> 4;
        int c  = idx & 15;
        int ci = NBR[off + (cl >> 3)] * 8 + (cl & 7);
        wsl[idx] = ws[(size_t)(jo * 16 + c) * CIN + ci];
    }
    if (tid < 16) bsl[tid] = bs[jo * 16 + tid];
    __syncthreads();

    float acc[16][4];
#pragma unroll
    for (int c = 0; c < 16; ++c)
#pragma unroll
        for (int i = 0; i < 4; ++i) acc[c][i] = bsl[c];

    const int p = 2 * t0;
    const float* xb = x + (size_t)b * CIN * T1;

    for (int cl = 0; cl < nci; ++cl) {
        const float* xc = xb + (size_t)cil[cl] * T1;
        float4 A  = *(const float4*)(xc + p);
        float4 Bv = *(const float4*)(xc + p + 4);
        float xv[4] = {A.x, A.z, Bv.x, Bv.z};
        const float* wr = &wsl[cl * 16];
#pragma unroll
        for (int c = 0; c < 16; ++c) {
            float w = wr[c];
#pragma unroll
            for (int i = 0; i < 4; ++i) acc[c][i] += w * xv[i];
        }
    }

    float* ob = s + ((size_t)b * COUTC + jo * 16) * TT2 + t0;
#pragma unroll
    for (int c = 0; c < 16; ++c) {
        float4 o;
        o.x = acc[c][0]; o.y = acc[c][1]; o.z = acc[c][2]; o.w = acc[c][3];
        *(float4*)(ob + (size_t)c * TT2) = o;
    }
}

// ---------------- Kernel D: finalize stats ----------------
__global__ void gn_final(const float* __restrict__ part, float* __restrict__ stats)
{
    int i = threadIdx.x;   // (b,g), 160 active
    if (i < BATCH * NGROUP) {
        int b = i / NGROUP, g = i % NGROUP;
        float s = 0.f, ss = 0.f;
        for (int sb = 0; sb < 5; ++sb)
            for (int xb = 0; xb < 4; ++xb) {
                size_t o = (((size_t)b * 50 + g * 5 + sb) * 4 + xb) * 2;
                s  += part[o];
                ss += part[o + 1];
            }
        const float invN = 1.0f / (float)(CPG * TT2);
        float mean = s * invN;
        float var  = ss * invN - mean * mean;
        stats[i * 2]     = mean;
        stats[i * 2 + 1] = rsqrtf(var + 1e-5f);
    }
}

// ---------------- Kernel E: streaming gn + add s + pool + PReLU -------------------
// grid (4, 28, 16), block 256.  y = n*2 + chalf (8 channels each). out: (B,224,4096)
__global__ __launch_bounds__(256) void final2(
    const float* __restrict__ h1, const float* __restrict__ s,
    const float* __restrict__ stats, const float* __restrict__ gamma,
    const float* __restrict__ beta, const float* __restrict__ a1,
    float* __restrict__ out)
{
    const int n     = blockIdx.y >> 1;
    const int chalf = blockIdx.y & 1;
    const int b     = blockIdx.z;
    const int tid   = threadIdx.x;
    const int t0    = (blockIdx.x * 256 + tid) * 4;

    int js[2];
    js[0] = PAIR_A[n];
    const int jb = PAIR_B[n];
    const int L = (jb >= 0) ? 2 : 1;
    js[1] = (jb >= 0) ? jb : js[0];

    __shared__ float ml[2][8], rl[2][8], btl[2][8];
    if (tid < 16) {
        int ji = tid >> 3, c8 = tid & 7;
        int ch = js[ji] * 16 + chalf * 8 + c8;
        int g  = ch / CPG;
        float m = stats[((size_t)b * NGROUP + g) * 2];
        float r = stats[((size_t)b * NGROUP + g) * 2 + 1];
        ml[ji][c8]  = m;
        rl[ji][c8]  = r * gamma[ch];
        btl[ji][c8] = beta[ch];
    }
    __syncthreads();

    const float alpha = a1[0];
    const float invL  = 1.0f / (float)L;
    const float* h1b = h1 + (size_t)b * COUTC * TT2;
    const float* sb  = s  + (size_t)b * COUTC * TT2;

    float acc[8][4];
#pragma unroll
    for (int c = 0; c < 8; ++c)
#pragma unroll
        for (int i = 0; i < 4; ++i) acc[c][i] = 0.f;

    for (int ji = 0; ji < L; ++ji) {
        const int jc0 = js[ji] * 16 + chalf * 8;
#pragma unroll
        for (int c = 0; c < 8; ++c) {
            size_t rowoff = (size_t)(jc0 + c) * TT2 + t0;
            float4 hv = *(const float4*)(h1b + rowoff);
            float4 sv = *(const float4*)(sb + rowoff);
            float m = ml[ji][c], r = rl[ji][c], bt = btl[ji][c];
            acc[c][0] += (hv.x - m) * r + bt + sv.x;
            acc[c][1] += (hv.y - m) * r + bt + sv.y;
            acc[c][2] += (hv.z - m) * r + bt + sv.z;
            acc[c][3] += (hv.w - m) * r + bt + sv.w;
        }
    }

    float* ob = out + ((size_t)b * 224 + n * 16 + chalf * 8) * TT2 + t0;
#pragma unroll
    for (int c = 0; c < 8; ++c) {
        float4 o;
#pragma unroll
        for (int i = 0; i < 4; ++i) {
            float v = acc[c][i] * invL;
            ((float*)&o)[i] = (v >= 0.f) ? v : alpha * v;
        }
        *(float4*)(ob + (size_t)c * TT2) = o;
    }
}

extern "C" void kernel_launch(void* const* d_in, const int* in_sizes, int n_in,
                              void* d_out, int out_size, void* d_ws, size_t ws_size,
                              hipStream_t stream) {
    const float* x     = (const float*)d_in[0];
    const float* w0    = (const float*)d_in[1];
    const float* b0    = (const float*)d_in[2];
    const float* a0    = (const float*)d_in[3];
    const float* w1    = (const float*)d_in[4];
    const float* b1    = (const float*)d_in[5];
    const float* gamma = (const float*)d_in[6];
    const float* beta  = (const float*)d_in[7];
    const float* ws    = (const float*)d_in[8];
    const float* bs    = (const float*)d_in[9];
    const float* a1    = (const float*)d_in[10];
    float* out = (float*)d_out;

    float* h0    = (float*)d_ws;                           // 26.2M floats; reused as s
    float* h1    = h0 + (size_t)BATCH * CIN * T1;          // 26.2M floats
    float* part  = h1 + (size_t)BATCH * COUTC * TT2;       // 6400 floats
    float* stats = part + (size_t)BATCH * 50 * 4 * 2;      // 320 floats
    float* sbuf  = h0;                                     // alias: h0 dead after conv1

    conv0_prelu<<<dim3(T1 / 1024, NJ, BATCH), 256, 0, stream>>>(x, w0, b0, a0, h0);
    conv1_gn<<<dim3(TT2 / 1024, NJ, BATCH), 256, 0, stream>>>(h0, w1, b1, h1, part);
    shortcut_k<<<dim3(TT2 / 1024, NJ, BATCH), 256, 0, stream>>>(x, ws, bs, sbuf);
    gn_final<<<1, 256, 0, stream>>>(part, stats);
    final2<<<dim3(TT2 / 1024, NPOOL * 2, BATCH), 256, 0, stream>>>(h1, sbuf, stats, gamma, beta, a1, out);
}